// Round 6
// baseline (47.934 us; speedup 1.0000x reference)
//
#include <hip/hip_runtime.h>
#include <math.h>

// OrthogonalButterfly: X (1024 x 8192) fp32, 20 butterfly layers, stride 2^(l%10).
// R5 lesson: spill fixed (VGPR 48, WRITE exactly 32MB) but latency/convoy-bound:
// 16-wave barrier groups x 10 syncs, occupancy 37%.
// R6: 512-thr blocks (8 cols x 1024 rows), grid 1024 -> 4 blocks/CU, 32 waves/CU,
// 8-wave barrier scope. 5 ownership phases of 4 layers each (P3 = {8,9,0,1}
// absorbs next round's s=1,2) -> 4 transposes, 7 barriers (was 5T/10B).
// Swizzle g(c)=((c&3)<<2)|((c>>2)<<4): b128 at floor, b32 <= 2-way (free).
//
// Phase row maps (thread sub in [0,64), element i in [0,16)):
//   P1: r = sub<<4 | i                         layers s=1,2,4,8    (SL=1,2,4,8)
//   P2: r = (sub&15) | i<<4 | (sub>>4)<<8      layers s=16..128    (SL=1,2,4,8)
//   P3: r = (i&3) | sub<<2 | (i>>2)<<8         layers s=256,512,1,2 (SL=4,8,1,2)
//   P4: r = (sub&3) | (i&3)<<2 | ((i>>2)&3)<<4 | (sub>>2)<<6
//                                              layers s=4..32      (SL=1,2,4,8)
//   P5: r = sub | (i&3)<<6 | (i>>2)<<8         layers s=64..512    (SL=1,2,4,8)

#define NROW   1024
#define BATCH  8192
#define DEPTH  20
#define NANG   512
#define NC     8
#define TAB_ELEMS (DEPTH * NANG)
#define TAB_BYTES ((size_t)TAB_ELEMS * 8)

__device__ __host__ __forceinline__ int rowP1(int sub, int i){ return (sub<<4)|i; }
__device__ __host__ __forceinline__ int rowP2(int sub, int i){ return (sub&15) | (i<<4) | ((sub>>4)<<8); }
__device__ __host__ __forceinline__ int rowP3(int sub, int i){ return (i&3) | (sub<<2) | ((i>>2)<<8); }
__device__ __host__ __forceinline__ int rowP4(int sub, int i){ return (sub&3) | ((i&3)<<2) | (((i>>2)&3)<<4) | ((sub>>2)<<6); }
__device__ __host__ __forceinline__ int rowP5(int sub, int i){ return sub | ((i&3)<<6) | ((i>>2)<<8); }

// ---------------- angle table build ----------------
// slot = 8*sub + p. For layer l with local stride SL and phase row map,
// pair p -> local i0 = 2*(p/SL)*SL + p%SL -> row r -> original angle index
// a = (r >> (sp+1))*s + (r & (s-1)), s = 2^sp, sp = l%10.
__global__ void build_tab_kernel(const float* __restrict__ ang,
                                 float2* __restrict__ tab) {
    int idx = blockIdx.x * blockDim.x + threadIdx.x;
    if (idx >= TAB_ELEMS) return;
    int l = idx >> 9;
    int slot = idx & (NANG - 1);
    int sub = slot >> 3, p = slot & 7;
    int sp = l % 10;
    int SL, ph;
    if (l < 4)       { ph = 0; SL = 1 << l; }
    else if (l < 8)  { ph = 1; SL = 1 << (l - 4); }
    else if (l < 12) { ph = 2; SL = (l == 8) ? 4 : (l == 9) ? 8 : (l == 10) ? 1 : 2; }
    else if (l < 16) { ph = 3; SL = 1 << (l - 12); }
    else             { ph = 4; SL = 1 << (l - 16); }
    int i0 = 2 * (p / SL) * SL + p % SL;
    int r;
    if (ph == 0)      r = rowP1(sub, i0);
    else if (ph == 1) r = rowP2(sub, i0);
    else if (ph == 2) r = rowP3(sub, i0);
    else if (ph == 3) r = rowP4(sub, i0);
    else              r = rowP5(sub, i0);
    int s = 1 << sp;
    int a = ((r >> (sp + 1)) << sp) | (r & (s - 1));
    float th = ang[l * NANG + a];
    float sv, cv;
    sincosf(th, &sv, &cv);
    tab[idx] = make_float2(cv, sv);
}

// ---------------- main kernel ----------------
__device__ __forceinline__ void rot(float& a, float& b, float cv, float sv) {
    float x0 = a, x1 = b;
    a = cv * x0 + sv * x1;
    b = cv * x1 - sv * x0;
}

// One layer on 16 register rows, local pair-stride SL. Table slice = 4 float4
// at tl + 8*sub (same addr for the 8 c-lanes -> broadcast).
template<int SL>
__device__ __forceinline__ void layer_tab(float y[16],
                                          const float2* __restrict__ tl,
                                          int sub) {
    const float4* q4 = reinterpret_cast<const float4*>(tl + 8 * sub);
    #pragma unroll
    for (int v = 0; v < 4; ++v) {
        float4 q = q4[v];
        int p0 = 2 * v, p1 = 2 * v + 1;
        int a0 = 2 * (p0 / SL) * SL + p0 % SL;   // constant-folds
        int a1 = 2 * (p1 / SL) * SL + p1 % SL;
        rot(y[a0], y[a0 + SL], q.x, q.y);
        rot(y[a1], y[a1 + SL], q.z, q.w);
    }
}

// Fallback without workspace: inline sincos.
template<int SL, int PH, int SP>
__device__ __forceinline__ void layer_notab(float y[16],
                                            const float* __restrict__ angL,
                                            int sub) {
    #pragma unroll
    for (int p = 0; p < 8; ++p) {
        int i0 = 2 * (p / SL) * SL + p % SL;
        int r;
        if (PH == 0)      r = rowP1(sub, i0);
        else if (PH == 1) r = rowP2(sub, i0);
        else if (PH == 2) r = rowP3(sub, i0);
        else if (PH == 3) r = rowP4(sub, i0);
        else              r = rowP5(sub, i0);
        int a = ((r >> (SP + 1)) << SP) | (r & ((1 << SP) - 1));
        float th = angL[a];
        float sv, cv;
        __sincosf(th, &sv, &cv);
        rot(y[i0], y[i0 + SL], cv, sv);
    }
}

// LDS: 8 cols x 1024 rows = 32KB. word addr = c<<10 | (r ^ g(c)).
__device__ __forceinline__ int gswz(int c) { return ((c & 3) << 2) | ((c >> 2) << 4); }

template<bool USE_TAB>
__global__ __launch_bounds__(512) void butterfly_kernel(
        const float* __restrict__ X, const float* __restrict__ ang,
        const float2* __restrict__ tab, float* __restrict__ out) {
    __shared__ float lds[NC * 1024];     // 32 KB -> 4 blocks/CU, 32 waves/CU
    int t = threadIdx.x;
    int c = t & (NC - 1);
    int sub = t >> 3;                    // [0,64)
    int bid = blockIdx.x;
    int L = ((bid & 7) << 7) | (bid >> 3);   // XCD-aware, bijective (1024 = 8*128)
    int col = L * NC + c;
    int xv = gswz(c);
    float* base = lds + (c << 10);

    float y[16];
    const float* Xp = X + col;
    #pragma unroll
    for (int i = 0; i < 16; ++i)
        y[i] = Xp[rowP1(sub, i) * BATCH];

    if (USE_TAB) {
        layer_tab<1>(y, tab + 0 * NANG, sub);    // s=1
        layer_tab<2>(y, tab + 1 * NANG, sub);    // s=2
        layer_tab<4>(y, tab + 2 * NANG, sub);    // s=4
        layer_tab<8>(y, tab + 3 * NANG, sub);    // s=8
    } else {
        layer_notab<1,0,0>(y, ang + 0 * NANG, sub);
        layer_notab<2,0,1>(y, ang + 1 * NANG, sub);
        layer_notab<4,0,2>(y, ang + 2 * NANG, sub);
        layer_notab<8,0,3>(y, ang + 3 * NANG, sub);
    }
    // T1: wr P1 (b128) / rd P2 (b32)
    #pragma unroll
    for (int u = 0; u < 4; ++u)
        *reinterpret_cast<float4*>(base + (((sub << 4) + 4 * u) ^ xv)) =
            make_float4(y[4*u], y[4*u+1], y[4*u+2], y[4*u+3]);
    __syncthreads();
    #pragma unroll
    for (int i = 0; i < 16; ++i)
        y[i] = base[rowP2(sub, i) ^ xv];

    if (USE_TAB) {
        layer_tab<1>(y, tab + 4 * NANG, sub);    // s=16
        layer_tab<2>(y, tab + 5 * NANG, sub);    // s=32
        layer_tab<4>(y, tab + 6 * NANG, sub);    // s=64
        layer_tab<8>(y, tab + 7 * NANG, sub);    // s=128
    } else {
        layer_notab<1,1,4>(y, ang + 4 * NANG, sub);
        layer_notab<2,1,5>(y, ang + 5 * NANG, sub);
        layer_notab<4,1,6>(y, ang + 6 * NANG, sub);
        layer_notab<8,1,7>(y, ang + 7 * NANG, sub);
    }
    // T2: wr P2 (b32) / rd P3 (b128)
    __syncthreads();
    #pragma unroll
    for (int i = 0; i < 16; ++i)
        base[rowP2(sub, i) ^ xv] = y[i];
    __syncthreads();
    #pragma unroll
    for (int k = 0; k < 4; ++k) {
        float4 v = *reinterpret_cast<const float4*>(base + (((sub << 2) | (k << 8)) ^ xv));
        y[4*k] = v.x; y[4*k+1] = v.y; y[4*k+2] = v.z; y[4*k+3] = v.w;
    }

    if (USE_TAB) {
        layer_tab<4>(y, tab +  8 * NANG, sub);   // s=256
        layer_tab<8>(y, tab +  9 * NANG, sub);   // s=512
        layer_tab<1>(y, tab + 10 * NANG, sub);   // s=1
        layer_tab<2>(y, tab + 11 * NANG, sub);   // s=2
    } else {
        layer_notab<4,2,8>(y, ang +  8 * NANG, sub);
        layer_notab<8,2,9>(y, ang +  9 * NANG, sub);
        layer_notab<1,2,0>(y, ang + 10 * NANG, sub);
        layer_notab<2,2,1>(y, ang + 11 * NANG, sub);
    }
    // T3: wr P3 (b128) / rd P4 (b32)
    __syncthreads();
    #pragma unroll
    for (int k = 0; k < 4; ++k)
        *reinterpret_cast<float4*>(base + (((sub << 2) | (k << 8)) ^ xv)) =
            make_float4(y[4*k], y[4*k+1], y[4*k+2], y[4*k+3]);
    __syncthreads();
    #pragma unroll
    for (int i = 0; i < 16; ++i)
        y[i] = base[rowP4(sub, i) ^ xv];

    if (USE_TAB) {
        layer_tab<1>(y, tab + 12 * NANG, sub);   // s=4
        layer_tab<2>(y, tab + 13 * NANG, sub);   // s=8
        layer_tab<4>(y, tab + 14 * NANG, sub);   // s=16
        layer_tab<8>(y, tab + 15 * NANG, sub);   // s=32
    } else {
        layer_notab<1,3,2>(y, ang + 12 * NANG, sub);
        layer_notab<2,3,3>(y, ang + 13 * NANG, sub);
        layer_notab<4,3,4>(y, ang + 14 * NANG, sub);
        layer_notab<8,3,5>(y, ang + 15 * NANG, sub);
    }
    // T4: wr P4 (b32) / rd P5 (b32)
    __syncthreads();
    #pragma unroll
    for (int i = 0; i < 16; ++i)
        base[rowP4(sub, i) ^ xv] = y[i];
    __syncthreads();
    #pragma unroll
    for (int i = 0; i < 16; ++i)
        y[i] = base[rowP5(sub, i) ^ xv];

    if (USE_TAB) {
        layer_tab<1>(y, tab + 16 * NANG, sub);   // s=64
        layer_tab<2>(y, tab + 17 * NANG, sub);   // s=128
        layer_tab<4>(y, tab + 18 * NANG, sub);   // s=256
        layer_tab<8>(y, tab + 19 * NANG, sub);   // s=512
    } else {
        layer_notab<1,4,6>(y, ang + 16 * NANG, sub);
        layer_notab<2,4,7>(y, ang + 17 * NANG, sub);
        layer_notab<4,4,8>(y, ang + 18 * NANG, sub);
        layer_notab<8,4,9>(y, ang + 19 * NANG, sub);
    }

    float* Op = out + col;
    #pragma unroll
    for (int i = 0; i < 16; ++i)
        Op[rowP5(sub, i) * BATCH] = y[i];
}

extern "C" void kernel_launch(void* const* d_in, const int* in_sizes, int n_in,
                              void* d_out, int out_size, void* d_ws, size_t ws_size,
                              hipStream_t stream) {
    (void)in_sizes; (void)n_in; (void)out_size;
    const float* X   = (const float*)d_in[0];
    const float* ang = (const float*)d_in[1];
    float* out = (float*)d_out;

    bool use_tab = (d_ws != nullptr) && (ws_size >= TAB_BYTES);
    if (use_tab) {
        float2* tab = (float2*)d_ws;
        build_tab_kernel<<<(TAB_ELEMS + 255) / 256, 256, 0, stream>>>(ang, tab);
        butterfly_kernel<true><<<1024, 512, 0, stream>>>(X, ang, tab, out);
    } else {
        butterfly_kernel<false><<<1024, 512, 0, stream>>>(X, ang, nullptr, out);
    }
}